// Round 5
// baseline (485.901 us; speedup 1.0000x reference)
//
#include <hip/hip_runtime.h>
#include <hip/hip_bf16.h>

#define B64   64
#define DH    512
#define HID   4096
#define VOC   50257
#define NSTEP 4
#define HSZ   (B64*DH)
#define NRB   32

typedef __attribute__((ext_vector_type(8)))  short bf16x8;
typedef __attribute__((ext_vector_type(4)))  float f32x4;
typedef __attribute__((ext_vector_type(16))) float f32x16;
typedef __hip_bfloat16 bf16;
typedef unsigned long long u64;

__device__ __forceinline__ bf16x8 ldg8(const bf16* p) {
    return *reinterpret_cast<const bf16x8*>(p);
}
// coherent 16B load: two 8B relaxed agent-scope atomic loads (bypass stale L2,
// served at the L3 coherence point; no acquire fence -> no L2 invalidate walk)
__device__ __forceinline__ bf16x8 ldc8(const bf16* p) {
    u64 a = __hip_atomic_load((const u64*)p,     __ATOMIC_RELAXED, __HIP_MEMORY_SCOPE_AGENT);
    u64 b = __hip_atomic_load((const u64*)p + 1, __ATOMIC_RELAXED, __HIP_MEMORY_SCOPE_AGENT);
    union { u64 q[2]; bf16x8 v; } u; u.q[0] = a; u.q[1] = b;
    return u.v;
}
__device__ __forceinline__ short f2bf(float x) {
    bf16 h = __float2bfloat16(x);
    return *reinterpret_cast<short*>(&h);
}
__device__ __forceinline__ bf16x8 cvt8(const float* p) {
    f32x4 a = *reinterpret_cast<const f32x4*>(p);
    f32x4 b = *reinterpret_cast<const f32x4*>(p + 4);
    bf16x8 r;
    r[0] = f2bf(a[0]); r[1] = f2bf(a[1]); r[2] = f2bf(a[2]); r[3] = f2bf(a[3]);
    r[4] = f2bf(b[0]); r[5] = f2bf(b[1]); r[6] = f2bf(b[2]); r[7] = f2bf(b[3]);
    return r;
}
__device__ __forceinline__ float sigmf(float x) { return 1.f / (1.f + __expf(-x)); }
__device__ __forceinline__ f32x4 mfma16(bf16x8 a, bf16x8 b, f32x4 c) {
    return __builtin_amdgcn_mfma_f32_16x16x32_bf16(a, b, c, 0, 0, 0);
}

// publish two adjacent bf16 h-values (lanes lr, lr^1) as one u32 via
// relaxed agent-scope atomic exchange: RMW completes at the L3 coherence
// point (tracked by vmcnt) -> no release fence / L2 writeback needed.
__device__ __forceinline__ void pub_pair(bf16* base, int idx_even, float v, int lr) {
    int mb = (int)(unsigned short)f2bf(v);
    int pb = __shfl_xor(mb, 1);
    if ((lr & 1) == 0) {
        unsigned pk = (unsigned)mb | ((unsigned)pb << 16);
        __hip_atomic_exchange((unsigned*)(base + idx_even), pk,
                              __ATOMIC_RELAXED, __HIP_MEMORY_SCOPE_AGENT);
    }
}

// ---------------------------------------------------------------------------
// k_prep: convert ip_w, hs, 4 GRU weight matrices to bf16; gather embed rows
// for steps 1..3 as bf16. One 8-elem chunk per thread.
// ---------------------------------------------------------------------------
__global__ __launch_bounds__(512) void k_prep(
    const float* __restrict__ hs, const float* __restrict__ ipw,
    const float* __restrict__ wi0, const float* __restrict__ wh0,
    const float* __restrict__ wi1, const float* __restrict__ wh1,
    const float* __restrict__ embed, const int* __restrict__ tids,
    bf16* __restrict__ hsb, bf16* __restrict__ ipwb,
    bf16* __restrict__ w0i, bf16* __restrict__ w0h,
    bf16* __restrict__ w1i, bf16* __restrict__ w1h,
    bf16* __restrict__ xemb)
{
    int c = blockIdx.x * 512 + threadIdx.x;
    const float* src; bf16* dst;
    if      (c < 262144) { size_t t = c;           src = ipw + t*8; dst = ipwb + t*8; }
    else if (c < 294912) { size_t t = c - 262144;  src = hs  + t*8; dst = hsb  + t*8; }
    else if (c < 393216) { size_t t = c - 294912;  src = wi0 + t*8; dst = w0i + t*8; }
    else if (c < 491520) { size_t t = c - 393216;  src = wh0 + t*8; dst = w0h + t*8; }
    else if (c < 589824) { size_t t = c - 491520;  src = wi1 + t*8; dst = w1i + t*8; }
    else if (c < 688128) { size_t t = c - 589824;  src = wh1 + t*8; dst = w1h + t*8; }
    else {
        int t = c - 688128;              // 12288 chunks = 192 rows x 64 chunks
        int r = t >> 6, j = t & 63;      // r = (s-1)*64 + b
        int s = r >> 6, b = r & 63;
        int rid = tids[b * NSTEP + s];
        src = embed + (size_t)rid * DH + j * 8;
        dst = xemb  + (size_t)r   * DH + j * 8;
    }
    *reinterpret_cast<bf16x8*>(dst) = cvt8(src);
}

// grid barrier among NRB blocks, ZERO cache maintenance: per-wave vmcnt(0)
// drain (atomics tracked there), block sync, relaxed add + relaxed poll.
__device__ __forceinline__ void gridbar(int* bar, int phase) {
    asm volatile("s_waitcnt vmcnt(0)" ::: "memory");
    __syncthreads();
    if (threadIdx.x == 0) {
        __hip_atomic_fetch_add(&bar[phase], 1, __ATOMIC_RELAXED, __HIP_MEMORY_SCOPE_AGENT);
        while (__hip_atomic_load(&bar[phase], __ATOMIC_RELAXED, __HIP_MEMORY_SCOPE_AGENT) < NRB)
            __builtin_amdgcn_s_sleep(2);
    }
    __syncthreads();
}

// ---------------------------------------------------------------------------
// k_rec v5: identical structure to v4 (32 blocks x 1024 thr, d-tile per block,
// weights in LDS, gi in regs, 5 grid barriers) EXCEPT all cross-block h-state
// traffic goes through L3-coherence-point atomics (pub_pair / ldc8) and the
// barrier carries no acquire/release -> no L2 writeback/invalidate walks.
// ---------------------------------------------------------------------------
__global__ __launch_bounds__(1024) void k_rec(
    const bf16* __restrict__ hsb, const bf16* __restrict__ ipwb, const float* __restrict__ ipb,
    const bf16* __restrict__ w0i, const bf16* __restrict__ w0h,
    const float* __restrict__ bi0, const float* __restrict__ bh0,
    const bf16* __restrict__ w1i, const bf16* __restrict__ w1h,
    const float* __restrict__ bi1, const float* __restrict__ bh1,
    const bf16* __restrict__ xemb,
    bf16* __restrict__ h0b3, bf16* __restrict__ h1b, bf16* __restrict__ hbig,
    int* __restrict__ bar)
{
    __shared__ __align__(16) char smem[155648];
    int tid = threadIdx.x, w = tid >> 6, lane = tid & 63;
    int lr = lane & 15, q = lane >> 4;

    float* red = (float*)smem;               // [16][4][64] (P0a only)
    float* sG  = (float*)(smem + 147456);    // [2][4][4][64]
    int d0 = blockIdx.x * 16;
    int g = w >> 2, mt = w & 3, m0 = mt * 16;
    int d = d0 + lr;
    float bR0 = bi0[d] + bh0[d],        bZ0 = bi0[DH+d] + bh0[DH+d];
    float biN0 = bi0[2*DH+d],           bhN0 = bh0[2*DH+d];
    float bR1 = bi1[d] + bh1[d],        bZ1 = bi1[DH+d] + bh1[DH+d];
    float biN1 = bi1[2*DH+d],           bhN1 = bh1[2*DH+d];
    f32x4 zero4 = {0.f, 0.f, 0.f, 0.f};
    float h0st[4] = {0,0,0,0}, h1st[4] = {0,0,0,0};

    // ---- P0a: h0 = hs @ ip_w^T + ip_b (K=4096, 4-way K-split; kc = w>>2)
    {
        int kc = w >> 2;
        const bf16* arow = hsb  + (size_t)(m0 + lr) * HID + kc * 1024 + q * 8;
        const bf16* brow = ipwb + (size_t)(d0 + lr) * HID + kc * 1024 + q * 8;
        f32x4 acc = zero4;
#pragma unroll 8
        for (int k0 = 0; k0 < 1024; k0 += 32)
            acc = mfma16(ldg8(arow + k0), ldg8(brow + k0), acc);
#pragma unroll
        for (int r = 0; r < 4; ++r) red[(w*4 + r)*64 + lane] = acc[r];
        __syncthreads();
        if (g == 2) {            // waves 8..11: epilogue owners
#pragma unroll
            for (int r = 0; r < 4; ++r) {
                float S = red[((mt    )*4 + r)*64 + lane]
                        + red[((mt + 4)*4 + r)*64 + lane]
                        + red[((mt + 8)*4 + r)*64 + lane]
                        + red[((mt +12)*4 + r)*64 + lane];
                float v = S + ipb[d];
                h0st[r] = v; h1st[r] = v;
                int row = m0 + q*4 + r;
                int idx = (row * DH + d) & ~1;
                pub_pair(h0b3, idx, v, lr);   // slot 0
                pub_pair(h1b,  idx, v, lr);   // buf 0
            }
        }
        __syncthreads();   // red region about to be overwritten by weights
    }

    // ---- weights -> LDS, XOR-swizzled rows (9216 chunks / 1024 thr = 9)
#pragma unroll
    for (int i = 0; i < 9; ++i) {
        int c = tid + 1024*i;
        int mi = c / 3072, rem = c % 3072;
        int gg = rem >> 10, r = (rem >> 6) & 15, kg = rem & 63;
        const bf16* base = (mi == 0) ? w0h : (mi == 1) ? w1h : w1i;
        const bf16* src = base + ((size_t)(gg*DH + d0 + r))*DH + kg*8;
        int dst = mi*49152 + gg*16384 + r*1024 + ((kg*16) ^ ((r & 7) << 4));
        *reinterpret_cast<bf16x8*>(smem + dst) = ldg8(src);
    }

    // ---- P0b: gi_s = x_s @ w_ih0^T (s=1..3), gate-local, kept in regs
    f32x4 gi1 = zero4, gi2 = zero4, gi3 = zero4;
    if (g < 3) {
        const bf16* wiR = w0i + (size_t)(g*DH + d0 + lr)*DH + q*8;
#pragma unroll
        for (int s = 1; s < 4; ++s) {
            const bf16* xr = xemb + (size_t)((s-1)*B64 + m0 + lr)*DH + q*8;
            f32x4 a = zero4;
#pragma unroll
            for (int k0 = 0; k0 < DH; k0 += 32)
                a = mfma16(ldg8(xr + k0), ldg8(wiR + k0), a);
            if (s == 1) gi1 = a; else if (s == 2) gi2 = a; else gi3 = a;
        }
    }
    gridbar(bar, 0);

    // ---- 4 steps x 2 layers; h0 triple-buffered, h1 double-buffered
    int c1 = 0;
#pragma unroll
    for (int s = 0; s < NSTEP; ++s) {
        int rsl = s % 3, rsw = (s + 1) % 3;
        f32x4 giv = (s == 0) ? zero4 : (s == 1) ? gi1 : (s == 2) ? gi2 : gi3;
        f32x4 aN = zero4;
        // layer 0: gh = h0 @ w0h^T (LDS weights, coherent A loads)
        if (g < 3) {
            const bf16* hr = h0b3 + (size_t)rsl*HSZ + (size_t)(m0 + lr)*DH + q*8;
            int bbase = g*16384 + lr*1024;
            f32x4 a = zero4;
#pragma unroll
            for (int k0 = 0; k0 < DH; k0 += 32) {
                int off = (k0*2 + q*16) ^ ((lr & 7) << 4);
                a = mfma16(ldc8(hr + k0),
                           *reinterpret_cast<const bf16x8*>(smem + bbase + off), a);
            }
            if (g < 2) {
#pragma unroll
                for (int r = 0; r < 4; ++r)
                    sG[((g*4 + mt)*4 + r)*64 + lane] = a[r] + giv[r];
            } else aN = a;
        }
        __syncthreads();
        if (g == 2) {
#pragma unroll
            for (int r = 0; r < 4; ++r) {
                float G0 = sG[((0*4 + mt)*4 + r)*64 + lane];
                float G1 = sG[((1*4 + mt)*4 + r)*64 + lane];
                float rg = sigmf(G0 + bR0);
                float zg = sigmf(G1 + bZ0);
                float ng = tanhf(giv[r] + biN0 + rg * (aN[r] + bhN0));
                h0st[r] = (1.f - zg) * ng + zg * h0st[r];
                int row = m0 + q*4 + r;
                int idx = (row * DH + d) & ~1;
                pub_pair(h0b3 + (size_t)rsw*HSZ, idx, h0st[r], lr);
            }
        }
        gridbar(bar, 1 + s);
        // layer 1: gates = h1 @ w1h^T + h0new @ w1i^T (LDS weights)
        f32x4 aH = zero4, aI = zero4;
        if (g < 3) {
            const bf16* h1r = h1b  + (size_t)c1 *HSZ + (size_t)(m0 + lr)*DH + q*8;
            const bf16* h0r = h0b3 + (size_t)rsw*HSZ + (size_t)(m0 + lr)*DH + q*8;
            int bH = 49152 + g*16384 + lr*1024;
            int bI = 98304 + g*16384 + lr*1024;
#pragma unroll
            for (int k0 = 0; k0 < DH; k0 += 32) {
                int off = (k0*2 + q*16) ^ ((lr & 7) << 4);
                aH = mfma16(ldc8(h1r + k0),
                            *reinterpret_cast<const bf16x8*>(smem + bH + off), aH);
                aI = mfma16(ldc8(h0r + k0),
                            *reinterpret_cast<const bf16x8*>(smem + bI + off), aI);
            }
            if (g < 2) {
#pragma unroll
                for (int r = 0; r < 4; ++r)
                    sG[((g*4 + mt)*4 + r)*64 + lane] = aH[r] + aI[r];
            }
        }
        __syncthreads();
        if (g == 2) {
#pragma unroll
            for (int r = 0; r < 4; ++r) {
                float G0 = sG[((0*4 + mt)*4 + r)*64 + lane];
                float G1 = sG[((1*4 + mt)*4 + r)*64 + lane];
                float rg = sigmf(G0 + bR1);
                float zg = sigmf(G1 + bZ1);
                float ng = tanhf(aI[r] + biN1 + rg * (aH[r] + bhN1));
                h1st[r] = (1.f - zg) * ng + zg * h1st[r];
                int row = m0 + q*4 + r;
                int idx = (row * DH + d) & ~1;
                pub_pair(h1b + (size_t)(c1 ^ 1)*HSZ, idx, h1st[r], lr);
                // hbig only consumed by the NEXT kernel -> plain paired store
                int mb = (int)(unsigned short)f2bf(h1st[r]);
                int pb = __shfl_xor(mb, 1);
                if ((lr & 1) == 0)
                    *(unsigned*)(hbig + (((size_t)(row * NSTEP + s) * DH + d) & ~(size_t)1)) =
                        (unsigned)mb | ((unsigned)pb << 16);
            }
        }
        c1 ^= 1;
        __syncthreads();   // sG WAR before next step's layer-0 writes
    }
}

// ---------------------------------------------------------------------------
// k_logits (round-2 shape): out = Hbig(256x512 bf16) @ out_w(50257x512 f32)^T
// 32x32x16 MFMA; block = 64 cols x 4 waves; wave = 4 m-tiles x 32 n-cols.
// A staged per 64-k chunk in XOR-swizzled LDS: conflict-free.
// ---------------------------------------------------------------------------
__global__ __launch_bounds__(256) void k_logits(
    const bf16* __restrict__ hbig, const float* __restrict__ outw, float* __restrict__ out)
{
    __shared__ __align__(16) bf16 sA[256 * 64];
    int t = threadIdx.x, w = t >> 6, lane = t & 63;
    int l32 = lane & 31, e = lane >> 5;
    int mh = w >> 1;                         // m-half (rows 0..127 / 128..255)
    int n = blockIdx.x * 64 + (w & 1) * 32 + l32;
    int nr = n < VOC ? n : VOC - 1;
    const float* brow = outw + (size_t)nr * DH;

    f32x16 acc[4];
#pragma unroll
    for (int i = 0; i < 4; ++i)
#pragma unroll
        for (int j = 0; j < 16; ++j) acc[i][j] = 0.f;

    for (int k0 = 0; k0 < DH; k0 += 64) {
#pragma unroll
        for (int i = 0; i < 8; ++i) {
            int c = i * 256 + t;
            int m = c >> 3, j = c & 7;
            *reinterpret_cast<bf16x8*>(&sA[m * 64 + ((j ^ (m & 7)) << 3)]) =
                ldg8(hbig + (size_t)m * DH + k0 + j * 8);
        }
        __syncthreads();
#pragma unroll
        for (int kk = 0; kk < 64; kk += 16) {
            bf16x8 bfrag = cvt8(brow + k0 + kk + e * 8);
            int g = (kk >> 3) + e;
#pragma unroll
            for (int mt2 = 0; mt2 < 4; ++mt2) {
                int r = (mh * 4 + mt2) * 32 + l32;
                bf16x8 afrag = *reinterpret_cast<const bf16x8*>(
                    &sA[r * 64 + ((g ^ (r & 7)) << 3)]);
                acc[mt2] = __builtin_amdgcn_mfma_f32_32x32x16_bf16(afrag, bfrag, acc[mt2], 0, 0, 0);
            }
        }
        __syncthreads();
    }
    if (n < VOC) {
#pragma unroll
        for (int mt2 = 0; mt2 < 4; ++mt2)
#pragma unroll
            for (int reg = 0; reg < 16; ++reg) {
                int m = (mh * 4 + mt2) * 32 + (reg & 3) + 8 * (reg >> 2) + 4 * e;
                out[(size_t)m * VOC + n] = acc[mt2][reg];
            }
    }
}

// ---------------------------------------------------------------------------
extern "C" void kernel_launch(void* const* d_in, const int* in_sizes, int n_in,
                              void* d_out, int out_size, void* d_ws, size_t ws_size,
                              hipStream_t stream) {
    const float* hs   = (const float*)d_in[0];
    const int*   tids = (const int*)d_in[1];
    const float* ipw  = (const float*)d_in[2];
    const float* ipb  = (const float*)d_in[3];
    const float* wih0 = (const float*)d_in[4];
    const float* whh0 = (const float*)d_in[5];
    const float* bih0 = (const float*)d_in[6];
    const float* bhh0 = (const float*)d_in[7];
    const float* wih1 = (const float*)d_in[8];
    const float* whh1 = (const float*)d_in[9];
    const float* bih1 = (const float*)d_in[10];
    const float* bhh1 = (const float*)d_in[11];
    const float* embed = (const float*)d_in[12];
    const float* outw  = (const float*)d_in[13];
    float* out = (float*)d_out;

    char* ws = (char*)d_ws;
    int*  bar  = (int*) (ws + 0);          // bars 0..4; memset below
    bf16* hsb  = (bf16*)(ws + 1024);       // 64x4096        (524288 B)
    bf16* ipwb = (bf16*)(ws + 525312);     // 512x4096       (4194304 B)
    bf16* w0i  = (bf16*)(ws + 4719616);    // 1536x512       (1572864 B each)
    bf16* w0h  = (bf16*)(ws + 6292480);
    bf16* w1i  = (bf16*)(ws + 7865344);
    bf16* w1h  = (bf16*)(ws + 9438208);
    bf16* xemb = (bf16*)(ws + 11011072);   // 3x64x512       (196608 B)
    bf16* h0b3 = (bf16*)(ws + 11207680);   // [3][64x512]    (196608 B)
    bf16* h1b  = (bf16*)(ws + 11404288);   // [2][64x512]    (131072 B)
    bf16* hbig = (bf16*)(ws + 11535360);   // 256x512 bf16, row m = b*4+s

    hipMemsetAsync(bar, 0, 256, stream);

    k_prep<<<1368, 512, 0, stream>>>(hs, ipw, wih0, whh0, wih1, whh1, embed, tids,
                                     hsb, ipwb, w0i, w0h, w1i, w1h, xemb);

    k_rec<<<NRB, 1024, 0, stream>>>(hsb, ipwb, ipb,
                                    w0i, w0h, bih0, bhh0,
                                    w1i, w1h, bih1, bhh1,
                                    xemb, h0b3, h1b, hbig, bar);

    k_logits<<<(VOC + 63) / 64, 256, 0, stream>>>(hbig, outw, out);
}

// Round 6
// 355.683 us; speedup vs baseline: 1.3661x; 1.3661x over previous
//
#include <hip/hip_runtime.h>
#include <hip/hip_bf16.h>

#define B64   64
#define DH    512
#define HID   4096
#define VOC   50257
#define NSTEP 4
#define HSZ   (B64*DH)
#define NL0   64
#define NL1   64

typedef __attribute__((ext_vector_type(8)))  short bf16x8;
typedef __attribute__((ext_vector_type(4)))  float f32x4;
typedef __attribute__((ext_vector_type(16))) float f32x16;
typedef __hip_bfloat16 bf16;

__device__ __forceinline__ bf16x8 ldg8(const bf16* p) {
    return *reinterpret_cast<const bf16x8*>(p);
}
__device__ __forceinline__ short f2bf(float x) {
    bf16 h = __float2bfloat16(x);
    return *reinterpret_cast<short*>(&h);
}
__device__ __forceinline__ bf16x8 cvt8(const float* p) {
    f32x4 a = *reinterpret_cast<const f32x4*>(p);
    f32x4 b = *reinterpret_cast<const f32x4*>(p + 4);
    bf16x8 r;
    r[0] = f2bf(a[0]); r[1] = f2bf(a[1]); r[2] = f2bf(a[2]); r[3] = f2bf(a[3]);
    r[4] = f2bf(b[0]); r[5] = f2bf(b[1]); r[6] = f2bf(b[2]); r[7] = f2bf(b[3]);
    return r;
}
__device__ __forceinline__ float sigmf(float x) { return 1.f / (1.f + __expf(-x)); }
__device__ __forceinline__ f32x4 mfma16(bf16x8 a, bf16x8 b, f32x4 c) {
    return __builtin_amdgcn_mfma_f32_16x16x32_bf16(a, b, c, 0, 0, 0);
}

// ---------------------------------------------------------------------------
// k_prep: convert ip_w, hs, 4 GRU weight matrices to bf16; gather embed rows
// for steps 1..3 as bf16.
// ---------------------------------------------------------------------------
__global__ __launch_bounds__(512) void k_prep(
    const float* __restrict__ hs, const float* __restrict__ ipw,
    const float* __restrict__ wi0, const float* __restrict__ wh0,
    const float* __restrict__ wi1, const float* __restrict__ wh1,
    const float* __restrict__ embed, const int* __restrict__ tids,
    bf16* __restrict__ hsb, bf16* __restrict__ ipwb,
    bf16* __restrict__ w0i, bf16* __restrict__ w0h,
    bf16* __restrict__ w1i, bf16* __restrict__ w1h,
    bf16* __restrict__ xemb)
{
    int c = blockIdx.x * 512 + threadIdx.x;
    const float* src; bf16* dst;
    if      (c < 262144) { size_t t = c;           src = ipw + t*8; dst = ipwb + t*8; }
    else if (c < 294912) { size_t t = c - 262144;  src = hs  + t*8; dst = hsb  + t*8; }
    else if (c < 393216) { size_t t = c - 294912;  src = wi0 + t*8; dst = w0i + t*8; }
    else if (c < 491520) { size_t t = c - 393216;  src = wh0 + t*8; dst = w0h + t*8; }
    else if (c < 589824) { size_t t = c - 491520;  src = wi1 + t*8; dst = w1i + t*8; }
    else if (c < 688128) { size_t t = c - 589824;  src = wh1 + t*8; dst = w1h + t*8; }
    else {
        int t = c - 688128;
        int r = t >> 6, j = t & 63;
        int s = r >> 6, b = r & 63;
        int rid = tids[b * NSTEP + s];
        src = embed + (size_t)rid * DH + j * 8;
        dst = xemb  + (size_t)r   * DH + j * 8;
    }
    *reinterpret_cast<bf16x8*>(dst) = cvt8(src);
}

// wait until bar[idx] >= target (relaxed poll, single acquire at exit)
__device__ __forceinline__ void barwait(int* bar, int idx, int target) {
    if (threadIdx.x == 0) {
        while (__hip_atomic_load(&bar[idx], __ATOMIC_RELAXED, __HIP_MEMORY_SCOPE_AGENT) < target)
            __builtin_amdgcn_s_sleep(1);
        (void)__hip_atomic_load(&bar[idx], __ATOMIC_ACQUIRE, __HIP_MEMORY_SCOPE_AGENT);
    }
    __syncthreads();
}
// block-wide: all prior stores done, then release-add
__device__ __forceinline__ void barbump(int* bar, int idx) {
    __syncthreads();
    if (threadIdx.x == 0)
        __hip_atomic_fetch_add(&bar[idx], 1, __ATOMIC_RELEASE, __HIP_MEMORY_SCOPE_AGENT);
}

// ---------------------------------------------------------------------------
// k_rec v6: 128 blocks x 512 thr. Layer-split + cooperative h-staging.
//   blocks 0..63  (L0): (d-tile 16, m-half 32). w0h slice in LDS (48KB).
//     Chain: P0 -> step0..3 of layer-0, gated only by L0-group barriers.
//     Per phase: stage h0[32 rows] -> swizzled LDS (4 ldg8/thread, 1 round
//     trip), MFMA from LDS, kc4-split reduce via sG, epilogue publishes.
//   blocks 64..127 (L1): (d-tile 16, m-half 32). w1h+w1i in LDS (96KB).
//     Step s waits L0 step s (h0new) + own step s-1 (h1). h1 staged in LDS;
//     h0new read as 4 independent ldg8/wave. sG overlays the h1 stage.
// bar: [0]=P0 done (64), [1+s]=L0 step s done (64), [8+s]=L1 step s done.
// ---------------------------------------------------------------------------
__global__ __launch_bounds__(512) void k_rec(
    const bf16* __restrict__ hsb, const bf16* __restrict__ ipwb, const float* __restrict__ ipb,
    const bf16* __restrict__ w0i, const bf16* __restrict__ w0h,
    const float* __restrict__ bi0, const float* __restrict__ bh0,
    const bf16* __restrict__ w1i, const bf16* __restrict__ w1h,
    const float* __restrict__ bi1, const float* __restrict__ bh1,
    const bf16* __restrict__ xemb,
    bf16* __restrict__ h0b3, bf16* __restrict__ h1b, bf16* __restrict__ hbig,
    int* __restrict__ bar)
{
    __shared__ __align__(16) char smem[131072];
    int tid = threadIdx.x, w = tid >> 6, lane = tid & 63;
    int lr = lane & 15, q = lane >> 4;
    int bid = blockIdx.x;
    bool isL0 = bid < NL0;
    int sub = isL0 ? bid : bid - NL0;
    int dt = sub >> 1, mh = sub & 1;
    int d0 = dt * 16, M0 = mh * 32;
    int mt = w >> 2, kc = w & 3;
    int m0 = M0 + mt * 16, ml = mt * 16;
    int d = d0 + lr;
    int row = m0 + q * 4 + kc;          // this thread's epilogue (row, d)

    if (isL0) {
        // =========================== LAYER 0 ===========================
        float bR0 = bi0[d] + bh0[d], bZ0 = bi0[DH+d] + bh0[DH+d];
        float biN0 = bi0[2*DH+d],    bhN0 = bh0[2*DH+d];
        float* sG = (float*)(smem + 81920);      // [3][8][4][64] f32 (24KB)
        f32x4 zero4 = {0.f,0.f,0.f,0.f};
        float h0st;

        // ---- P0a: h0_0 = hs @ ip_w^T + ip_b (wave kc-slice K=1024)
        {
            const bf16* arow = hsb  + (size_t)(m0 + lr) * HID + kc * 1024 + q * 8;
            const bf16* brow = ipwb + (size_t)(d0 + lr) * HID + kc * 1024 + q * 8;
            f32x4 acc = zero4;
#pragma unroll 8
            for (int k0 = 0; k0 < 1024; k0 += 32)
                acc = mfma16(ldg8(arow + k0), ldg8(brow + k0), acc);
#pragma unroll
            for (int r = 0; r < 4; ++r) sG[(w*4 + r)*64 + lane] = acc[r];
            __syncthreads();
            float S = 0.f;
#pragma unroll
            for (int j = 0; j < 4; ++j) S += sG[((mt*4 + j)*4 + kc)*64 + lane];
            float v = S + ipb[d];
            h0st = v;
            bf16 vb = __float2bfloat16(v);
            h0b3[row * DH + d] = vb;   // slot 0
            h1b[row * DH + d] = vb;    // h1 buf 0
            __syncthreads();
        }

        // ---- stage w0h slice -> LDS [3][16][512] swizzled (48KB at 0)
#pragma unroll
        for (int i = 0; i < 6; ++i) {
            int c = tid + 512*i;
            int g = c >> 10, r = (c >> 6) & 15, kg = c & 63;
            const bf16* src = w0h + ((size_t)(g*DH + d0 + r))*DH + kg*8;
            int dst = g*16384 + r*1024 + ((kg*16) ^ ((r & 7) << 4));
            *reinterpret_cast<bf16x8*>(smem + dst) = ldg8(src);
        }

        // ---- gi_s = x_s @ w_ih0^T (s=1..3) -> per-thread scalars
        float giR[NSTEP] = {0,0,0,0}, giZ[NSTEP] = {0,0,0,0}, giN[NSTEP] = {0,0,0,0};
#pragma unroll
        for (int s = 1; s < NSTEP; ++s) {
            const bf16* xr = xemb + (size_t)((s-1)*B64 + m0 + lr)*DH + kc*128 + q*8;
#pragma unroll
            for (int g = 0; g < 3; ++g) {
                const bf16* wr = w0i + (size_t)(g*DH + d0 + lr)*DH + kc*128 + q*8;
                f32x4 a = zero4;
#pragma unroll
                for (int kt = 0; kt < 4; ++kt)
                    a = mfma16(ldg8(xr + kt*32), ldg8(wr + kt*32), a);
#pragma unroll
                for (int r = 0; r < 4; ++r) sG[((g*8 + w)*4 + r)*64 + lane] = a[r];
            }
            __syncthreads();
            float sR = 0, sZ = 0, sN = 0;
#pragma unroll
            for (int j = 0; j < 4; ++j) {
                sR += sG[((0*8 + mt*4 + j)*4 + kc)*64 + lane];
                sZ += sG[((1*8 + mt*4 + j)*4 + kc)*64 + lane];
                sN += sG[((2*8 + mt*4 + j)*4 + kc)*64 + lane];
            }
            giR[s] = sR; giZ[s] = sZ; giN[s] = sN;
            __syncthreads();
        }
        barbump(bar, 0);

        // ---- steps 0..3
        for (int s = 0; s < NSTEP; ++s) {
            barwait(bar, s == 0 ? 0 : s, NL0);
            if (s == 3) barwait(bar, 8 + 0, NL1);   // WAR: slot1 vs L1 step0
            // stage h0[s%3][M0..M0+31][*] -> sH (32KB at 49152), swizzled
            const bf16* hsrc = h0b3 + (size_t)(s % 3) * HSZ;
#pragma unroll
            for (int i = 0; i < 4; ++i) {
                int c = tid + 512*i;
                int rr = c >> 6, kg = c & 63;
                int dst = 49152 + rr*1024 + ((kg*16) ^ ((rr & 7) << 4));
                *reinterpret_cast<bf16x8*>(smem + dst) =
                    ldg8(hsrc + (size_t)(M0 + rr)*DH + kg*8);
            }
            __syncthreads();
            // MFMA from LDS
            bf16x8 af[4];
            int arow = ml + lr;
#pragma unroll
            for (int kt = 0; kt < 4; ++kt) {
                int ke = (kc*128 + kt*32 + q*8) * 2;
                af[kt] = *reinterpret_cast<const bf16x8*>(
                    smem + 49152 + arow*1024 + (ke ^ ((arow & 7) << 4)));
            }
            f32x4 ag[3];
#pragma unroll
            for (int g = 0; g < 3; ++g) {
                f32x4 a = zero4;
#pragma unroll
                for (int kt = 0; kt < 4; ++kt) {
                    int ke = (kc*128 + kt*32 + q*8) * 2;
                    bf16x8 b = *reinterpret_cast<const bf16x8*>(
                        smem + g*16384 + lr*1024 + (ke ^ ((lr & 7) << 4)));
                    a = mfma16(af[kt], b, a);
                }
                ag[g] = a;
            }
#pragma unroll
            for (int g = 0; g < 3; ++g)
#pragma unroll
                for (int r = 0; r < 4; ++r)
                    sG[((g*8 + w)*4 + r)*64 + lane] = ag[g][r];
            __syncthreads();
            float G0 = 0, G1 = 0, GN = 0;
#pragma unroll
            for (int j = 0; j < 4; ++j) {
                G0 += sG[((0*8 + mt*4 + j)*4 + kc)*64 + lane];
                G1 += sG[((1*8 + mt*4 + j)*4 + kc)*64 + lane];
                GN += sG[((2*8 + mt*4 + j)*4 + kc)*64 + lane];
            }
            float rg = sigmf(G0 + giR[s] + bR0);
            float zg = sigmf(G1 + giZ[s] + bZ0);
            float ng = tanhf(giN[s] + biN0 + rg * (GN + bhN0));
            h0st = (1.f - zg) * ng + zg * h0st;
            h0b3[(size_t)((s + 1) % 3) * HSZ + row * DH + d] = __float2bfloat16(h0st);
            barbump(bar, 1 + s);
        }
    } else {
        // =========================== LAYER 1 ===========================
        float bR1 = bi1[d] + bh1[d], bZ1 = bi1[DH+d] + bh1[DH+d];
        float biN1 = bi1[2*DH+d],    bhN1 = bh1[2*DH+d];
        float* sG = (float*)(smem + 98304);      // [4][8][4][64] f32 (32KB), overlays sH1
        f32x4 zero4 = {0.f,0.f,0.f,0.f};

        // ---- stage w1h (0) + w1i (49152) slices -> LDS (96KB), swizzled
#pragma unroll
        for (int i = 0; i < 12; ++i) {
            int c = tid + 512*i;
            int mi = c / 3072, rem = c % 3072;
            int g = rem >> 10, r = (rem >> 6) & 15, kg = rem & 63;
            const bf16* base = mi ? w1i : w1h;
            const bf16* src = base + ((size_t)(g*DH + d0 + r))*DH + kg*8;
            int dst = mi*49152 + g*16384 + r*1024 + ((kg*16) ^ ((r & 7) << 4));
            *reinterpret_cast<bf16x8*>(smem + dst) = ldg8(src);
        }
        barwait(bar, 0, NL0);
        float h1st = __bfloat162float(h1b[row * DH + d]);

        int c1 = 0;
        for (int s = 0; s < NSTEP; ++s) {
            barwait(bar, 1 + s, NL0);                 // h0_{s+1} ready
            if (s > 0) barwait(bar, 8 + s - 1, NL1);  // own group lockstep
            // independent h0new loads (A operand for w1i path)
            const bf16* h0r = h0b3 + (size_t)((s + 1) % 3) * HSZ
                              + (size_t)(m0 + lr)*DH + kc*128 + q*8;
            bf16x8 a0[4];
#pragma unroll
            for (int kt = 0; kt < 4; ++kt) a0[kt] = ldg8(h0r + kt*32);
            // stage h1[c1][M0..M0+31][*] -> sH1 (32KB at 98304), swizzled
            const bf16* h1src = h1b + (size_t)c1 * HSZ;
#pragma unroll
            for (int i = 0; i < 4; ++i) {
                int c = tid + 512*i;
                int rr = c >> 6, kg = c & 63;
                int dst = 98304 + rr*1024 + ((kg*16) ^ ((rr & 7) << 4));
                *reinterpret_cast<bf16x8*>(smem + dst) =
                    ldg8(h1src + (size_t)(M0 + rr)*DH + kg*8);
            }
            __syncthreads();
            bf16x8 a1[4];
            int arow = ml + lr;
#pragma unroll
            for (int kt = 0; kt < 4; ++kt) {
                int ke = (kc*128 + kt*32 + q*8) * 2;
                a1[kt] = *reinterpret_cast<const bf16x8*>(
                    smem + 98304 + arow*1024 + (ke ^ ((arow & 7) << 4)));
            }
            f32x4 comb0 = zero4, comb1 = zero4, hN = zero4, iN = zero4;
#pragma unroll
            for (int g = 0; g < 3; ++g) {
                f32x4 aH = zero4, aI = zero4;
#pragma unroll
                for (int kt = 0; kt < 4; ++kt) {
                    int ke = (kc*128 + kt*32 + q*8) * 2;
                    bf16x8 bH = *reinterpret_cast<const bf16x8*>(
                        smem + g*16384 + lr*1024 + (ke ^ ((lr & 7) << 4)));
                    bf16x8 bI = *reinterpret_cast<const bf16x8*>(
                        smem + 49152 + g*16384 + lr*1024 + (ke ^ ((lr & 7) << 4)));
                    aH = mfma16(a1[kt], bH, aH);
                    aI = mfma16(a0[kt], bI, aI);
                }
                if (g == 0) { comb0 = aH; comb0[0] += aI[0]; comb0[1] += aI[1]; comb0[2] += aI[2]; comb0[3] += aI[3]; }
                else if (g == 1) { comb1 = aH; comb1[0] += aI[0]; comb1[1] += aI[1]; comb1[2] += aI[2]; comb1[3] += aI[3]; }
                else { hN = aH; iN = aI; }
            }
            __syncthreads();   // all waves done reading sH1 before sG overlay
#pragma unroll
            for (int r = 0; r < 4; ++r) {
                sG[((0*8 + w)*4 + r)*64 + lane] = comb0[r];
                sG[((1*8 + w)*4 + r)*64 + lane] = comb1[r];
                sG[((2*8 + w)*4 + r)*64 + lane] = hN[r];
                sG[((3*8 + w)*4 + r)*64 + lane] = iN[r];
            }
            __syncthreads();
            float GR = 0, GZ = 0, GhN = 0, GiN = 0;
#pragma unroll
            for (int j = 0; j < 4; ++j) {
                GR  += sG[((0*8 + mt*4 + j)*4 + kc)*64 + lane];
                GZ  += sG[((1*8 + mt*4 + j)*4 + kc)*64 + lane];
                GhN += sG[((2*8 + mt*4 + j)*4 + kc)*64 + lane];
                GiN += sG[((3*8 + mt*4 + j)*4 + kc)*64 + lane];
            }
            float rg = sigmf(GR + bR1);
            float zg = sigmf(GZ + bZ1);
            float ng = tanhf(GiN + biN1 + rg * (GhN + bhN1));
            h1st = (1.f - zg) * ng + zg * h1st;
            bf16 hvb = __float2bfloat16(h1st);
            h1b[(size_t)(c1 ^ 1) * HSZ + row * DH + d] = hvb;
            hbig[(size_t)(row * NSTEP + s) * DH + d] = hvb;
            c1 ^= 1;
            barbump(bar, 8 + s);
        }
    }
}

// ---------------------------------------------------------------------------
// k_logits (round-2 shape, known good): out = Hbig @ out_w^T
// ---------------------------------------------------------------------------
__global__ __launch_bounds__(256) void k_logits(
    const bf16* __restrict__ hbig, const float* __restrict__ outw, float* __restrict__ out)
{
    __shared__ __align__(16) bf16 sA[256 * 64];
    int t = threadIdx.x, w = t >> 6, lane = t & 63;
    int l32 = lane & 31, e = lane >> 5;
    int mh = w >> 1;
    int n = blockIdx.x * 64 + (w & 1) * 32 + l32;
    int nr = n < VOC ? n : VOC - 1;
    const float* brow = outw + (size_t)nr * DH;

    f32x16 acc[4];
#pragma unroll
    for (int i = 0; i < 4; ++i)
#pragma unroll
        for (int j = 0; j < 16; ++j) acc[i][j] = 0.f;

    for (int k0 = 0; k0 < DH; k0 += 64) {
#pragma unroll
        for (int i = 0; i < 8; ++i) {
            int c = i * 256 + t;
            int m = c >> 3, j = c & 7;
            *reinterpret_cast<bf16x8*>(&sA[m * 64 + ((j ^ (m & 7)) << 3)]) =
                ldg8(hbig + (size_t)m * DH + k0 + j * 8);
        }
        __syncthreads();
#pragma unroll
        for (int kk = 0; kk < 64; kk += 16) {
            bf16x8 bfrag = cvt8(brow + k0 + kk + e * 8);
            int g = (kk >> 3) + e;
#pragma unroll
            for (int mt2 = 0; mt2 < 4; ++mt2) {
                int r = (mh * 4 + mt2) * 32 + l32;
                bf16x8 afrag = *reinterpret_cast<const bf16x8*>(
                    &sA[r * 64 + ((g ^ (r & 7)) << 3)]);
                acc[mt2] = __builtin_amdgcn_mfma_f32_32x32x16_bf16(afrag, bfrag, acc[mt2], 0, 0, 0);
            }
        }
        __syncthreads();
    }
    if (n < VOC) {
#pragma unroll
        for (int mt2 = 0; mt2 < 4; ++mt2)
#pragma unroll
            for (int reg = 0; reg < 16; ++reg) {
                int m = (mh * 4 + mt2) * 32 + (reg & 3) + 8 * (reg >> 2) + 4 * e;
                out[(size_t)m * VOC + n] = acc[mt2][reg];
            }
    }
}

// ---------------------------------------------------------------------------
extern "C" void kernel_launch(void* const* d_in, const int* in_sizes, int n_in,
                              void* d_out, int out_size, void* d_ws, size_t ws_size,
                              hipStream_t stream) {
    const float* hs   = (const float*)d_in[0];
    const int*   tids = (const int*)d_in[1];
    const float* ipw  = (const float*)d_in[2];
    const float* ipb  = (const float*)d_in[3];
    const float* wih0 = (const float*)d_in[4];
    const float* whh0 = (const float*)d_in[5];
    const float* bih0 = (const float*)d_in[6];
    const float* bhh0 = (const float*)d_in[7];
    const float* wih1 = (const float*)d_in[8];
    const float* whh1 = (const float*)d_in[9];
    const float* bih1 = (const float*)d_in[10];
    const float* bhh1 = (const float*)d_in[11];
    const float* embed = (const float*)d_in[12];
    const float* outw  = (const float*)d_in[13];
    float* out = (float*)d_out;

    char* ws = (char*)d_ws;
    int*  bar  = (int*) (ws + 0);          // bar[0..12]; memset below
    bf16* hsb  = (bf16*)(ws + 1024);       // 64x4096        (524288 B)
    bf16* ipwb = (bf16*)(ws + 525312);     // 512x4096       (4194304 B)
    bf16* w0i  = (bf16*)(ws + 4719616);    // 1536x512       (1572864 B each)
    bf16* w0h  = (bf16*)(ws + 6292480);
    bf16* w1i  = (bf16*)(ws + 7865344);
    bf16* w1h  = (bf16*)(ws + 9438208);
    bf16* xemb = (bf16*)(ws + 11011072);   // 3x64x512       (196608 B)
    bf16* h0b3 = (bf16*)(ws + 11207680);   // [3][64x512]    (196608 B)
    bf16* h1b  = (bf16*)(ws + 11404288);   // [2][64x512]    (131072 B)
    bf16* hbig = (bf16*)(ws + 11535360);   // 256x512 bf16, row m = b*4+s

    hipMemsetAsync(bar, 0, 256, stream);

    k_prep<<<1368, 512, 0, stream>>>(hs, ipw, wih0, whh0, wih1, whh1, embed, tids,
                                     hsb, ipwb, w0i, w0h, w1i, w1h, xemb);

    k_rec<<<NL0 + NL1, 512, 0, stream>>>(hsb, ipwb, ipb,
                                         w0i, w0h, bih0, bhh0,
                                         w1i, w1h, bih1, bhh1,
                                         xemb, h0b3, h1b, hbig, bar);

    k_logits<<<(VOC + 63) / 64, 256, 0, stream>>>(hbig, outw, out);
}